// Round 4
// baseline (235.359 us; speedup 1.0000x reference)
//
#include <hip/hip_runtime.h>
#include <cstdint>

#define BB 32
#define PP 131072
#define NEG_RATIO 3

typedef float v4f __attribute__((ext_vector_type(4)));
typedef float v2f __attribute__((ext_vector_type(2)));

// Workspace accumulators (zeroed via hipMemsetAsync each launch).
struct Ws {
  float sum_sl1[BB];     // per-batch sum of smoothL1 * pos
  float sum_ce_all[BB];  // per-batch sum of CE over all priors
  float sum_ce_pos[BB];  // per-batch sum of CE over positives
  float ce_neg[BB];      // per-batch CE sum over selected negatives (case-2 only)
  int   num_pos[BB];
};

__device__ __forceinline__ float sl1sum(v4f a, v4f b) {
  float dx = fabsf(a.x - b.x), dy = fabsf(a.y - b.y),
        dz = fabsf(a.z - b.z), dw = fabsf(a.w - b.w);
  float sx = dx < 1.0f ? 0.5f * dx * dx : dx - 0.5f;
  float sy = dy < 1.0f ? 0.5f * dy * dy : dy - 0.5f;
  float sz = dz < 1.0f ? 0.5f * dz * dz : dz - 0.5f;
  float sw = dw < 1.0f ? 0.5f * dw * dw : dw - 0.5f;
  return (sx + sy) + (sz + sw);
}

__device__ __forceinline__ float ce_fast(float c0, float c1, int t) {
  float m = fmaxf(c0, c1);
  float d = fabsf(c0 - c1);
  float lse = m + __logf(1.0f + __expf(-d));
  return lse - (t ? c1 : c0);
}

// exact-ish version for the (never-taken on bench data) select path
__device__ __forceinline__ float ce_of(float c0, float c1, int t) {
  float m = fmaxf(c0, c1), mn = fminf(c0, c1);
  float lse = m + log1pf(expf(mn - m));
  return lse - (t ? c1 : c0);
}

// ---------------- K_fused: all element-wise reductions in one pass ----------------
// Block b covers priors [512b, 512b+512); thread t handles p0 = 512b+t and
// p0+256. Every load instruction is lane-unit-stride (fully coalesced).
// The 8 loads are issued via asm volatile so the compiler CANNOT serialize
// them (rounds 1-3: VGPR 20-28 => ~1 load in flight => ~2.5 TB/s wall).
// The closing s_waitcnt ties all results as "+v" so no use can hoist above it.
__global__ __launch_bounds__(256) void k_fused(
    const v4f* __restrict__ loc, const v2f* __restrict__ cf2,
    const v4f* __restrict__ loct, const int* __restrict__ tt,
    Ws* __restrict__ ws) {
  const int tid = threadIdx.x;
  const int b = blockIdx.x;
  const int batch = b >> 8;        // 256 blocks per batch (131072/512)
  const int p0 = b * 512 + tid;    // second prior is p0 + 256

  v4f l0, l1, g0, g1;
  v2f c0, c1;
  int t0, t1;
  asm volatile("global_load_dwordx4 %0, %1, off" : "=v"(l0) : "v"(loc + p0));
  asm volatile("global_load_dwordx4 %0, %1, off" : "=v"(l1) : "v"(loc + p0 + 256));
  asm volatile("global_load_dwordx4 %0, %1, off" : "=v"(g0) : "v"(loct + p0));
  asm volatile("global_load_dwordx4 %0, %1, off" : "=v"(g1) : "v"(loct + p0 + 256));
  asm volatile("global_load_dwordx2 %0, %1, off" : "=v"(c0) : "v"(cf2 + p0));
  asm volatile("global_load_dwordx2 %0, %1, off offset:2048" : "=v"(c1) : "v"(cf2 + p0));
  asm volatile("global_load_dword %0, %1, off" : "=v"(t0) : "v"(tt + p0));
  asm volatile("global_load_dword %0, %1, off offset:1024" : "=v"(t1) : "v"(tt + p0));
  asm volatile("s_waitcnt vmcnt(0)"
               : "+v"(l0), "+v"(l1), "+v"(g0), "+v"(g1),
                 "+v"(c0), "+v"(c1), "+v"(t0), "+v"(t1));

  const float ce0 = ce_fast(c0.x, c0.y, t0);
  const float ce1 = ce_fast(c1.x, c1.y, t1);
  const float s0 = sl1sum(l0, g0);
  const float s1 = sl1sum(l1, g1);
  const float m0 = t0 > 0 ? 1.0f : 0.0f;
  const float m1 = t1 > 0 ? 1.0f : 0.0f;

  float a_all = ce0 + ce1;
  float a_pos = m0 * ce0 + m1 * ce1;
  float a_sl1 = m0 * s0 + m1 * s1;
  int   a_np  = (t0 > 0) + (t1 > 0);

#pragma unroll
  for (int off = 32; off; off >>= 1) {
    a_all += __shfl_down(a_all, off);
    a_pos += __shfl_down(a_pos, off);
    a_sl1 += __shfl_down(a_sl1, off);
    a_np  += __shfl_down(a_np, off);
  }

  __shared__ float s1s[4], s2s[4], s3s[4];
  __shared__ int s4s[4];
  const int wave = tid >> 6, lane = tid & 63;
  if (lane == 0) { s1s[wave] = a_sl1; s2s[wave] = a_all; s3s[wave] = a_pos; s4s[wave] = a_np; }
  __syncthreads();
  if (tid == 0) {
    atomicAdd(&ws->sum_sl1[batch],    (s1s[0] + s1s[1]) + (s1s[2] + s1s[3]));
    atomicAdd(&ws->sum_ce_all[batch], (s2s[0] + s2s[1]) + (s2s[2] + s2s[3]));
    atomicAdd(&ws->sum_ce_pos[batch], (s3s[0] + s3s[1]) + (s3s[2] + s3s[3]));
    atomicAdd(&ws->num_pos[batch],     s4s[0] + s4s[1] + s4s[2] + s4s[3]);
  }
}

// ---------------- K2: general top-k negative selection (case 2) ----------------
// Only runs for batches where num_neg < (P - num_pos). For the bench data this
// never triggers (num_neg = P-1 >= M), so the block exits immediately.
__global__ __launch_bounds__(256) void k_select(
    const float2* __restrict__ conf, const int* __restrict__ conft,
    Ws* __restrict__ ws) {
  const int b = blockIdx.x;
  const int npos = ws->num_pos[b];
  const long long M = (long long)PP - npos;
  long long k = (long long)NEG_RATIO * npos;
  if (k > PP - 1) k = PP - 1;
  if (k >= M) return;   // case 1: sel == everything, finalize handles it
  if (k <= 0) return;   // no negatives selected

  const int tid = threadIdx.x;
  const int rowbase = b * PP;

  __shared__ unsigned hist[2048];
  __shared__ unsigned sh_prefix;
  __shared__ long long sh_kk;

  unsigned prefix = 0;
  long long kk = k;
  const int shifts[3] = {21, 10, 0};
  const int widths[3] = {11, 11, 10};

  for (int pass = 0; pass < 3; ++pass) {
    const int shift = shifts[pass], width = widths[pass];
    const unsigned mask = (1u << width) - 1u;
    for (int j = tid; j < 2048; j += 256) hist[j] = 0;
    __syncthreads();
    for (int i = tid; i < PP; i += 256) {
      const float2 c = conf[rowbase + i];
      const int t = conft[rowbase + i];
      const float score = (t > 0) ? 0.0f : ce_of(c.x, c.y, t);
      const unsigned u = __float_as_uint(score);
      const bool match = (pass == 0) || ((u >> (shift + width)) == prefix);
      if (match) atomicAdd(&hist[(u >> shift) & mask], 1u);
    }
    __syncthreads();
    if (tid == 0) {
      long long c = 0;
      int d = (int)mask;
      for (; d >= 0; --d) {
        c += hist[d];
        if (c >= kk) break;
      }
      if (d < 0) d = 0;  // safety; invariant guarantees break
      sh_prefix = (prefix << width) | (unsigned)d;
      sh_kk = kk - (c - (long long)hist[d]);
    }
    __syncthreads();
    prefix = sh_prefix;
    kk = sh_kk;
    __syncthreads();
  }

  // prefix == T bits (k-th largest score). kk = #ties to include, ascending
  // index order (stable argsort semantics).
  const unsigned Tbits = prefix;
  double local_ce = 0.0;
  __shared__ unsigned wavecnt[4];
  __shared__ long long s_rt;
  if (tid == 0) s_rt = 0;
  __syncthreads();
  const int lane = tid & 63, wave = tid >> 6;

  for (int basei = 0; basei < PP; basei += 256) {
    const int i = basei + tid;
    const float2 c = conf[rowbase + i];
    const int t = conft[rowbase + i];
    const float ce = ce_of(c.x, c.y, t);
    const float score = (t > 0) ? 0.0f : ce;
    const unsigned u = __float_as_uint(score);
    const bool gt = u > Tbits;
    const bool eq = (u == Tbits);
    const unsigned long long bal = __ballot(eq ? 1 : 0);
    if (lane == 0) wavecnt[wave] = (unsigned)__popcll(bal);
    __syncthreads();
    long long cross = s_rt;
    for (int w = 0; w < wave; ++w) cross += wavecnt[w];
    const long long myord = cross + __popcll(bal & ((1ULL << lane) - 1ULL));
    if (gt || (eq && myord < kk)) local_ce += (double)ce;
    __syncthreads();
    if (tid == 0) s_rt += (long long)wavecnt[0] + wavecnt[1] + wavecnt[2] + wavecnt[3];
    __syncthreads();
  }

#pragma unroll
  for (int off = 32; off; off >>= 1) local_ce += __shfl_down(local_ce, off);
  __shared__ double s_ce[4];
  if (lane == 0) s_ce[wave] = local_ce;
  __syncthreads();
  if (tid == 0) ws->ce_neg[b] = (float)(s_ce[0] + s_ce[1] + s_ce[2] + s_ce[3]);
}

// ---------------- K3: finalize ----------------
__global__ __launch_bounds__(64) void k_final(const Ws* __restrict__ ws,
                                              float* __restrict__ out) {
  const int tid = threadIdx.x;
  double np_d = 0.0, ce_sel = 0.0, cnt = 0.0, sl1 = 0.0;
  if (tid < BB) {
    const int npos = ws->num_pos[tid];
    const long long M = (long long)PP - npos;
    long long k = (long long)NEG_RATIO * npos;
    if (k > PP - 1) k = PP - 1;
    np_d = (double)npos;
    sl1 = (double)ws->sum_sl1[tid];
    if (k >= M) {  // case 1: sel covers every prior
      ce_sel = (double)ws->sum_ce_all[tid];
      cnt = (double)PP;
    } else {
      const long long kc = k > 0 ? k : 0;
      ce_sel = (double)ws->sum_ce_pos[tid] + (double)ws->ce_neg[tid];
      cnt = (double)(npos + kc);
    }
  }
#pragma unroll
  for (int off = 32; off; off >>= 1) {
    np_d   += __shfl_down(np_d, off);
    ce_sel += __shfl_down(ce_sel, off);
    cnt    += __shfl_down(cnt, off);
    sl1    += __shfl_down(sl1, off);
  }
  if (tid == 0) {
    const double N = np_d;
    out[0] = (float)(sl1 / (4.0 * N * N));
    out[1] = (float)(ce_sel / cnt / N);
  }
}

extern "C" void kernel_launch(void* const* d_in, const int* in_sizes, int n_in,
                              void* d_out, int out_size, void* d_ws, size_t ws_size,
                              hipStream_t stream) {
  const v4f*    loc   = (const v4f*)d_in[0];
  const v2f*    cf2   = (const v2f*)d_in[1];
  const float2* conf  = (const float2*)d_in[1];
  const v4f*    loct  = (const v4f*)d_in[2];
  const int*    cnft  = (const int*)d_in[3];
  Ws* ws = (Ws*)d_ws;

  hipMemsetAsync(d_ws, 0, sizeof(Ws), stream);
  k_fused<<<dim3((BB * PP) / 512), dim3(256), 0, stream>>>(loc, cf2, loct, cnft, ws);
  k_select<<<dim3(BB), dim3(256), 0, stream>>>(conf, cnft, ws);
  k_final<<<dim3(1), dim3(64), 0, stream>>>(ws, (float*)d_out);
}

// Round 5
// 213.975 us; speedup vs baseline: 1.0999x; 1.0999x over previous
//
#include <hip/hip_runtime.h>
#include <cstdint>

#define BB 32
#define PP 131072
#define NEG_RATIO 3

typedef float v4f __attribute__((ext_vector_type(4)));
typedef float v2f __attribute__((ext_vector_type(2)));

#define TO_LDS(p) ((__attribute__((address_space(3))) void*)(p))
#define TO_GLB(p) ((const __attribute__((address_space(1))) void*)(p))

// Workspace accumulators (zeroed via hipMemsetAsync each launch).
struct Ws {
  float sum_sl1[BB];     // per-batch sum of smoothL1 * pos
  float sum_ce_all[BB];  // per-batch sum of CE over all priors
  float sum_ce_pos[BB];  // per-batch sum of CE over positives
  float ce_neg[BB];      // per-batch CE sum over selected negatives (case-2 only)
  int   num_pos[BB];
};

__device__ __forceinline__ float sl1sum(v4f a, v4f b) {
  float dx = fabsf(a.x - b.x), dy = fabsf(a.y - b.y),
        dz = fabsf(a.z - b.z), dw = fabsf(a.w - b.w);
  float sx = dx < 1.0f ? 0.5f * dx * dx : dx - 0.5f;
  float sy = dy < 1.0f ? 0.5f * dy * dy : dy - 0.5f;
  float sz = dz < 1.0f ? 0.5f * dz * dz : dz - 0.5f;
  float sw = dw < 1.0f ? 0.5f * dw * dw : dw - 0.5f;
  return (sx + sy) + (sz + sw);
}

__device__ __forceinline__ float ce_fast(float c0, float c1, int t) {
  float m = fmaxf(c0, c1);
  float d = fabsf(c0 - c1);
  float lse = m + __logf(1.0f + __expf(-d));
  return lse - (t ? c1 : c0);
}

// exact-ish version for the (never-taken on bench data) select path
__device__ __forceinline__ float ce_of(float c0, float c1, int t) {
  float m = fmaxf(c0, c1), mn = fminf(c0, c1);
  float lse = m + log1pf(expf(mn - m));
  return lse - (t ? c1 : c0);
}

// ---------------- K_fused: LDS-DMA streamed reduction ----------------
// 1024 blocks x 256 thr = 4096 waves; wave w owns 1024 contiguous priors of
// batch w>>7, processed as 16 tiles of 64. Each tile is staged into a
// wave-PRIVATE double-buffered LDS region via global_load_lds (results have
// no VGPR live range -> the RA cannot serialize them; rounds 1-4 all
// collapsed to ~1 load in flight). No __syncthreads in the stream loop.
__global__ __launch_bounds__(256) void k_fused(
    const char* __restrict__ locB, const char* __restrict__ confB,
    const char* __restrict__ loctB, const char* __restrict__ ttB,
    Ws* __restrict__ ws) {
  __shared__ char smem[4 * 6144];  // per-wave 6 KB: 2 buffers x 3072 B
  const int lane = threadIdx.x & 63;
  const int wib  = threadIdx.x >> 6;
  const int w    = blockIdx.x * 4 + wib;   // 0..4095
  const int batch = w >> 7;                // 128 waves per batch
  const int chunk = w & 127;
  const int start = batch * PP + chunk * 1024;

  char* wbase = smem + wib * 6144;

  // per-lane global byte pointers for tile 0
  const char* gl = locB  + (size_t)(start + lane) * 16;
  const char* gg = loctB + (size_t)(start + lane) * 16;
  const char* gc = confB + (size_t)start * 8 + (size_t)lane * 4;
  const char* gt = ttB   + (size_t)(start + lane) * 4;

  // prologue: stage tile 0 into buffer 0
  {
    char* s = wbase;
    __builtin_amdgcn_global_load_lds(TO_GLB(gl),       TO_LDS(s +    0), 16, 0, 0);
    __builtin_amdgcn_global_load_lds(TO_GLB(gg),       TO_LDS(s + 1024), 16, 0, 0);
    __builtin_amdgcn_global_load_lds(TO_GLB(gc),       TO_LDS(s + 2048),  4, 0, 0);
    __builtin_amdgcn_global_load_lds(TO_GLB(gc + 256), TO_LDS(s + 2304),  4, 0, 0);
    __builtin_amdgcn_global_load_lds(TO_GLB(gt),       TO_LDS(s + 2560),  4, 0, 0);
  }

  float a_all = 0.f, a_pos = 0.f, a_sl1 = 0.f;
  int np = 0;

  for (int it = 0; it < 16; ++it) {
    char* cur = wbase + (it & 1) * 3072;
    if (it < 15) {
      // prefetch tile it+1 into the other buffer
      char* s = wbase + ((it + 1) & 1) * 3072;
      const char* pl = gl + (size_t)(it + 1) * 1024;
      const char* pg = gg + (size_t)(it + 1) * 1024;
      const char* pc = gc + (size_t)(it + 1) * 512;
      const char* pt = gt + (size_t)(it + 1) * 256;
      __builtin_amdgcn_global_load_lds(TO_GLB(pl),       TO_LDS(s +    0), 16, 0, 0);
      __builtin_amdgcn_global_load_lds(TO_GLB(pg),       TO_LDS(s + 1024), 16, 0, 0);
      __builtin_amdgcn_global_load_lds(TO_GLB(pc),       TO_LDS(s + 2048),  4, 0, 0);
      __builtin_amdgcn_global_load_lds(TO_GLB(pc + 256), TO_LDS(s + 2304),  4, 0, 0);
      __builtin_amdgcn_global_load_lds(TO_GLB(pt),       TO_LDS(s + 2560),  4, 0, 0);
      // vmcnt retires in issue order: <=5 outstanding => current tile landed
      asm volatile("s_waitcnt vmcnt(5)" ::: "memory");
    } else {
      asm volatile("s_waitcnt vmcnt(0)" ::: "memory");
    }

    const v4f l = *(const v4f*)(cur +    0 + lane * 16);
    const v4f g = *(const v4f*)(cur + 1024 + lane * 16);
    const v2f c = *(const v2f*)(cur + 2048 + lane * 8);
    const int t = *(const int*)(cur + 2560 + lane * 4);

    const float ce = ce_fast(c.x, c.y, t);
    const float s  = sl1sum(l, g);
    const float m  = t > 0 ? 1.0f : 0.0f;
    a_all += ce;
    a_pos += m * ce;
    a_sl1 += m * s;
    np    += (t > 0);
  }

  // wave-level reduction; one set of atomics per wave (128 waves per batch)
#pragma unroll
  for (int off = 32; off; off >>= 1) {
    a_all += __shfl_down(a_all, off);
    a_pos += __shfl_down(a_pos, off);
    a_sl1 += __shfl_down(a_sl1, off);
    np    += __shfl_down(np, off);
  }
  if (lane == 0) {
    atomicAdd(&ws->sum_ce_all[batch], a_all);
    atomicAdd(&ws->sum_ce_pos[batch], a_pos);
    atomicAdd(&ws->sum_sl1[batch],    a_sl1);
    atomicAdd(&ws->num_pos[batch],    np);
  }
}

// ---------------- K2: general top-k negative selection (case 2) ----------------
// Only runs for batches where num_neg < (P - num_pos). For the bench data this
// never triggers (num_neg = P-1 >= M), so the block exits immediately.
__global__ __launch_bounds__(256) void k_select(
    const float2* __restrict__ conf, const int* __restrict__ conft,
    Ws* __restrict__ ws) {
  const int b = blockIdx.x;
  const int npos = ws->num_pos[b];
  const long long M = (long long)PP - npos;
  long long k = (long long)NEG_RATIO * npos;
  if (k > PP - 1) k = PP - 1;
  if (k >= M) return;   // case 1: sel == everything, finalize handles it
  if (k <= 0) return;   // no negatives selected

  const int tid = threadIdx.x;
  const int rowbase = b * PP;

  __shared__ unsigned hist[2048];
  __shared__ unsigned sh_prefix;
  __shared__ long long sh_kk;

  unsigned prefix = 0;
  long long kk = k;
  const int shifts[3] = {21, 10, 0};
  const int widths[3] = {11, 11, 10};

  for (int pass = 0; pass < 3; ++pass) {
    const int shift = shifts[pass], width = widths[pass];
    const unsigned mask = (1u << width) - 1u;
    for (int j = tid; j < 2048; j += 256) hist[j] = 0;
    __syncthreads();
    for (int i = tid; i < PP; i += 256) {
      const float2 c = conf[rowbase + i];
      const int t = conft[rowbase + i];
      const float score = (t > 0) ? 0.0f : ce_of(c.x, c.y, t);
      const unsigned u = __float_as_uint(score);
      const bool match = (pass == 0) || ((u >> (shift + width)) == prefix);
      if (match) atomicAdd(&hist[(u >> shift) & mask], 1u);
    }
    __syncthreads();
    if (tid == 0) {
      long long c = 0;
      int d = (int)mask;
      for (; d >= 0; --d) {
        c += hist[d];
        if (c >= kk) break;
      }
      if (d < 0) d = 0;  // safety; invariant guarantees break
      sh_prefix = (prefix << width) | (unsigned)d;
      sh_kk = kk - (c - (long long)hist[d]);
    }
    __syncthreads();
    prefix = sh_prefix;
    kk = sh_kk;
    __syncthreads();
  }

  // prefix == T bits (k-th largest score). kk = #ties to include, ascending
  // index order (stable argsort semantics).
  const unsigned Tbits = prefix;
  double local_ce = 0.0;
  __shared__ unsigned wavecnt[4];
  __shared__ long long s_rt;
  if (tid == 0) s_rt = 0;
  __syncthreads();
  const int lane = tid & 63, wave = tid >> 6;

  for (int basei = 0; basei < PP; basei += 256) {
    const int i = basei + tid;
    const float2 c = conf[rowbase + i];
    const int t = conft[rowbase + i];
    const float ce = ce_of(c.x, c.y, t);
    const float score = (t > 0) ? 0.0f : ce;
    const unsigned u = __float_as_uint(score);
    const bool gt = u > Tbits;
    const bool eq = (u == Tbits);
    const unsigned long long bal = __ballot(eq ? 1 : 0);
    if (lane == 0) wavecnt[wave] = (unsigned)__popcll(bal);
    __syncthreads();
    long long cross = s_rt;
    for (int w = 0; w < wave; ++w) cross += wavecnt[w];
    const long long myord = cross + __popcll(bal & ((1ULL << lane) - 1ULL));
    if (gt || (eq && myord < kk)) local_ce += (double)ce;
    __syncthreads();
    if (tid == 0) s_rt += (long long)wavecnt[0] + wavecnt[1] + wavecnt[2] + wavecnt[3];
    __syncthreads();
  }

#pragma unroll
  for (int off = 32; off; off >>= 1) local_ce += __shfl_down(local_ce, off);
  __shared__ double s_ce[4];
  if (lane == 0) s_ce[wave] = local_ce;
  __syncthreads();
  if (tid == 0) ws->ce_neg[b] = (float)(s_ce[0] + s_ce[1] + s_ce[2] + s_ce[3]);
}

// ---------------- K3: finalize ----------------
__global__ __launch_bounds__(64) void k_final(const Ws* __restrict__ ws,
                                              float* __restrict__ out) {
  const int tid = threadIdx.x;
  double np_d = 0.0, ce_sel = 0.0, cnt = 0.0, sl1 = 0.0;
  if (tid < BB) {
    const int npos = ws->num_pos[tid];
    const long long M = (long long)PP - npos;
    long long k = (long long)NEG_RATIO * npos;
    if (k > PP - 1) k = PP - 1;
    np_d = (double)npos;
    sl1 = (double)ws->sum_sl1[tid];
    if (k >= M) {  // case 1: sel covers every prior
      ce_sel = (double)ws->sum_ce_all[tid];
      cnt = (double)PP;
    } else {
      const long long kc = k > 0 ? k : 0;
      ce_sel = (double)ws->sum_ce_pos[tid] + (double)ws->ce_neg[tid];
      cnt = (double)(npos + kc);
    }
  }
#pragma unroll
  for (int off = 32; off; off >>= 1) {
    np_d   += __shfl_down(np_d, off);
    ce_sel += __shfl_down(ce_sel, off);
    cnt    += __shfl_down(cnt, off);
    sl1    += __shfl_down(sl1, off);
  }
  if (tid == 0) {
    const double N = np_d;
    out[0] = (float)(sl1 / (4.0 * N * N));
    out[1] = (float)(ce_sel / cnt / N);
  }
}

extern "C" void kernel_launch(void* const* d_in, const int* in_sizes, int n_in,
                              void* d_out, int out_size, void* d_ws, size_t ws_size,
                              hipStream_t stream) {
  const char*   locB  = (const char*)d_in[0];
  const char*   confB = (const char*)d_in[1];
  const float2* conf  = (const float2*)d_in[1];
  const char*   loctB = (const char*)d_in[2];
  const char*   ttB   = (const char*)d_in[3];
  const int*    cnft  = (const int*)d_in[3];
  Ws* ws = (Ws*)d_ws;

  hipMemsetAsync(d_ws, 0, sizeof(Ws), stream);
  k_fused<<<dim3(1024), dim3(256), 0, stream>>>(locB, confB, loctB, ttB, ws);
  k_select<<<dim3(BB), dim3(256), 0, stream>>>(conf, cnft, ws);
  k_final<<<dim3(1), dim3(64), 0, stream>>>(ws, (float*)d_out);
}